// Round 6
// baseline (196.737 us; speedup 1.0000x reference)
//
#include <hip/hip_runtime.h>
#include <hip/hip_bf16.h>

#define D_MODEL 1024
#define D_STATE 16
#define L_SEQ 2048
#define B_SZ 4
#define M_ROWS (B_SZ * L_SEQ)   // 8192
#define N_CHUNK 32               // chunks per sequence
#define C_LEN 64                 // timesteps per chunk (32*64 = 2048)

typedef __attribute__((ext_vector_type(8))) short short8;
typedef __attribute__((ext_vector_type(4))) float f32x4;

#define SBAR()  asm volatile("s_barrier" ::: "memory")
#define GATE(N) asm volatile("s_waitcnt vmcnt(" #N ") lgkmcnt(0)\n\ts_barrier" ::: "memory")

typedef const unsigned short __attribute__((address_space(1))) gas_us;
typedef unsigned short __attribute__((address_space(3))) las_us;
static __device__ __forceinline__ void gload16(const unsigned short* g, unsigned short* l) {
    // global -> LDS DMA, 16B per lane, dest = wave-uniform base + lane*16
    __builtin_amdgcn_global_load_lds((gas_us*)g, (las_us*)l, 16, 0, 0);
}

static __device__ __forceinline__ unsigned short f2bf(float f) {
    unsigned int u = __float_as_uint(f);
    unsigned int r = (u + 0x7FFFu + ((u >> 16) & 1u)) >> 16;   // RNE
    return (unsigned short)r;
}
static __device__ __forceinline__ float bf2f(unsigned short u) {
    return __uint_as_float(((unsigned int)u) << 16);
}

// ---------------- fused prep: LN rows + weight bf16 conversion ----------------
__global__ __launch_bounds__(256) void prep_kernel(const float* __restrict__ x,
                                                   const float* __restrict__ g,
                                                   const float* __restrict__ b,
                                                   unsigned short* __restrict__ xn,
                                                   const float* __restrict__ in_w,
                                                   unsigned short* __restrict__ w1,
                                                   const float* __restrict__ out_w,
                                                   unsigned short* __restrict__ w2) {
    __shared__ float sbuf[8];
    int bid = blockIdx.x;
    int t = threadIdx.x;
    if (bid < M_ROWS) {
        int row = bid;
        const float4* xr = (const float4*)(x + (size_t)row * D_MODEL);
        float4 v = xr[t];
        float s  = v.x + v.y + v.z + v.w;
        float ss = v.x * v.x + v.y * v.y + v.z * v.z + v.w * v.w;
        #pragma unroll
        for (int o = 32; o > 0; o >>= 1) {
            s  += __shfl_down(s,  o);
            ss += __shfl_down(ss, o);
        }
        int wid = t >> 6;
        if ((t & 63) == 0) { sbuf[wid] = s; sbuf[4 + wid] = ss; }
        __syncthreads();
        float S  = sbuf[0] + sbuf[1] + sbuf[2] + sbuf[3];
        float SS = sbuf[4] + sbuf[5] + sbuf[6] + sbuf[7];
        float mu  = S * (1.0f / D_MODEL);
        float var = SS * (1.0f / D_MODEL) - mu * mu;
        float inv = rsqrtf(var + 1e-5f);
        float4 gv = ((const float4*)g)[t];
        float4 bv = ((const float4*)b)[t];
        ushort4 o;
        o.x = f2bf((v.x - mu) * inv * gv.x + bv.x);
        o.y = f2bf((v.y - mu) * inv * gv.y + bv.y);
        o.z = f2bf((v.z - mu) * inv * gv.z + bv.z);
        o.w = f2bf((v.w - mu) * inv * gv.w + bv.w);
        ((ushort4*)(xn + (size_t)row * D_MODEL))[t] = o;
    } else if (bid < M_ROWS + 2048) {
        int i = (bid - M_ROWS) * 256 + t;
        float4 v = ((const float4*)in_w)[i];
        ushort4 o;
        o.x = f2bf(v.x); o.y = f2bf(v.y); o.z = f2bf(v.z); o.w = f2bf(v.w);
        ((ushort4*)w1)[i] = o;
    } else {
        int i = (bid - M_ROWS - 2048) * 256 + t;
        float4 v = ((const float4*)out_w)[i];
        ushort4 o;
        o.x = f2bf(v.x); o.y = f2bf(v.y); o.z = f2bf(v.z); o.w = f2bf(v.w);
        ((ushort4*)w2)[i] = o;
    }
}

// ============================================================================
// GEMM1: m201-style 8-phase schedule. 256x256 tile, BK=64, 2 K-tile LDS
// double-buffer (128KB). 8 waves (2m x 4n), wave tile 128x64, acc[8][4].
// Half-tile = one matrix x one K-half (256r x 32k = 16KB, 2 gload16/thread).
// Per iter (2 K-tiles Te/buf0, To/buf1): 8 phases, each =
//   {4-8 ds_read_b128, stage 1 half-tile, SBAR, lgkm0, 16 MFMA (setprio), SBAR}
// vmcnt(4) gates at phases 4 and 8 only (never drain in steady state).
// Stage map (verified ledger): ph1:(To).kh1A ph2:(To).kh1B ph3:(Te+2).kh0A
// ph4:(Te+2).kh0B+G4 ph5:(Te+2).kh1A ph6:(Te+2).kh1B ph7:(To+2).kh0A
// ph8:(To+2).kh0B+G4.  WAR: every stage-target's last reads complete at a
// barrier >= 1 phase earlier (lgkm0 pre-MFMA + phase-end barrier).
// LDS per buffer (shorts): A-kh0@0 A-kh1@8192 B-kh0@16384 B-kh1@24576.
// Subtile [16r][32k] XOR swizzle identical to the proven R2-R5 scheme.
// ============================================================================
#define STG(B_, MAT_, KH_, GPTR_, KOFF_) do { \
    unsigned short* d_ = lbase + (B_)*32768 + (MAT_)*16384 + (KH_)*8192 + wave*1024; \
    gload16((GPTR_) + (KOFF_), d_); \
    gload16((GPTR_) + 16*K + (KOFF_), d_ + 512); } while(0)

#define PH(B_, KS_, MG_, READB_, STAGE_, TAIL_) { \
    if (READB_) { \
        _Pragma("unroll") for (int j_ = 0; j_ < 4; ++j_) \
            bv[j_] = *(const short8*)(ldsB + (B_)*65536 + (KS_)*16384 + (wn*4 + j_)*1024); \
    } \
    short8 av[4]; \
    _Pragma("unroll") for (int i_ = 0; i_ < 4; ++i_) \
        av[i_] = *(const short8*)(ldsA + (B_)*65536 + (KS_)*16384 + (wm*8 + (MG_)*4 + i_)*1024); \
    STAGE_; \
    SBAR(); \
    asm volatile("s_waitcnt lgkmcnt(0)" ::: "memory"); \
    __builtin_amdgcn_s_setprio(1); \
    _Pragma("unroll") for (int i_ = 0; i_ < 4; ++i_) { \
        _Pragma("unroll") for (int j_ = 0; j_ < 4; ++j_) \
            acc[(MG_)*4 + i_][j_] = __builtin_amdgcn_mfma_f32_16x16x32_bf16( \
                av[i_], bv[j_], acc[(MG_)*4 + i_][j_], 0, 0, 0); } \
    __builtin_amdgcn_s_setprio(0); \
    TAIL_; \
}

__global__ __launch_bounds__(512, 1) void gemm1_kernel(const unsigned short* __restrict__ A,
                                                       const unsigned short* __restrict__ Bt,
                                                       const float* __restrict__ bias,
                                                       unsigned short* __restrict__ u_bf,
                                                       unsigned short* __restrict__ zs) {
    __shared__ __align__(16) unsigned short lds[2][32768];   // 128 KB
    const int K = D_MODEL;

    int t = threadIdx.x;
    int lane = t & 63;
    int wave = t >> 6;
    int wm = wave >> 2;          // 0..1 -> A half (128 rows)
    int wn = wave & 3;           // 0..3 -> B quarter (64 rows)

    // XCD swizzle: 256 blocks = 32m x 8n; XCD x owns m-panels [4x,4x+4), all n
    int bid = blockIdx.x;
    int swz = (bid & 7) * 32 + (bid >> 3);
    int m0 = (swz >> 3) * 256;
    int n0 = (swz & 7) * 256;

    // staging source (inverse-swizzled): lane -> (row = sub*16 + (lane>>2), k)
    int srow = lane >> 2;
    int sk = ((lane & 3) * 8) ^ ((lane & 32) >> 1);
    const unsigned short* gA = A  + (size_t)(m0 + wave * 32 + srow) * K + sk;
    const unsigned short* gB = Bt + (size_t)(n0 + wave * 32 + srow) * K + sk;

    unsigned short* lbase = &lds[0][0];

    // swizzled ds_read bases (bytes)
    int off_base = (lane & 15) * 64 + (((lane >> 4) * 16) ^ ((lane & 8) * 4));
    const char* ldsA = (const char*)lbase + off_base;
    const char* ldsB = (const char*)lbase + 32768 + off_base;

    f32x4 acc[8][4] = {};
    short8 bv[4];

    // prologue: T0 fully (8 loads), T1.kh0 (4 loads); GATE(4) -> T0 landed
    STG(0, 0, 0, gA, 0);  STG(0, 1, 0, gB, 0);
    STG(0, 0, 1, gA, 32); STG(0, 1, 1, gB, 32);
    STG(1, 0, 0, gA, 64); STG(1, 1, 0, gB, 64);
    GATE(4);

    int ko = 0;
    #pragma unroll 1
    for (int it = 0; it < 7; ++it) {
        PH(0, 0, 0, true,  STG(1, 0, 1, gA, ko + 96),  SBAR());
        PH(0, 0, 1, false, STG(1, 1, 1, gB, ko + 96),  SBAR());
        PH(0, 1, 0, true,  STG(0, 0, 0, gA, ko + 128), SBAR());
        PH(0, 1, 1, false, STG(0, 1, 0, gB, ko + 128), GATE(4));
        PH(1, 0, 0, true,  STG(0, 0, 1, gA, ko + 160), SBAR());
        PH(1, 0, 1, false, STG(0, 1, 1, gB, ko + 160), SBAR());
        PH(1, 1, 0, true,  STG(1, 0, 0, gA, ko + 192), SBAR());
        PH(1, 1, 1, false, STG(1, 1, 0, gB, ko + 192), GATE(4));
        ko += 128;
    }
    // peeled last iter (T14/buf0, T15/buf1): stage only T15.kh1; GATE(0) @ph4
    PH(0, 0, 0, true,  STG(1, 0, 1, gA, ko + 96), SBAR());
    PH(0, 0, 1, false, STG(1, 1, 1, gB, ko + 96), SBAR());
    PH(0, 1, 0, true,  (void)0, SBAR());
    PH(0, 1, 1, false, (void)0, GATE(0));
    PH(1, 0, 0, true,  (void)0, SBAR());
    PH(1, 0, 1, false, (void)0, SBAR());
    PH(1, 1, 0, true,  (void)0, SBAR());
    PH(1, 1, 1, false, (void)0, (void)0);

    // epilogue: row-major line completion. C/D: col=lane&15, row=quad*4+r
    int col = lane & 15;
    int quad = lane >> 4;
    float bs[4];
    #pragma unroll
    for (int jf = 0; jf < 4; ++jf) bs[jf] = bias[n0 + wn * 64 + jf * 16 + col];
    bool isU = (n0 < D_MODEL);               // uniform per block
    int nbase = isU ? (n0 + wn * 64 + col) : (n0 - D_MODEL + wn * 64 + col);
    unsigned short* obase = isU ? u_bf : zs;
    #pragma unroll
    for (int i = 0; i < 8; ++i) {
        #pragma unroll
        for (int r = 0; r < 4; ++r) {
            int m = m0 + wm * 128 + i * 16 + quad * 4 + r;
            unsigned short* orow = obase + (size_t)m * D_MODEL + nbase;
            #pragma unroll
            for (int jf = 0; jf < 4; ++jf) {
                float v = acc[i][jf][r] + bs[jf];
                if (!isU) v = v / (1.0f + __expf(-v));
                orow[jf * 16] = f2bf(v);
            }
        }
    }
}

// ============================================================================
// GEMM2: 128x256 tile, BK=32, 4 LDS slots (24KB each), lead-3 pipeline.
// Unchanged (isolation).
// ============================================================================
#define MFMA16(ACC, AV, BV) { \
    _Pragma("unroll") for (int i_ = 0; i_ < 4; ++i_) { \
        _Pragma("unroll") for (int jf_ = 0; jf_ < 4; ++jf_) \
            ACC[i_][jf_] = __builtin_amdgcn_mfma_f32_16x16x32_bf16( \
                AV[i_], BV[jf_], ACC[i_][jf_], 0, 0, 0); } }

#define STAGE2(J) { size_t ko_ = (size_t)(J) * 32; int so_ = ((J) & 3) * 12288; \
    gload16(pA0 + ko_, dA + so_); gload16(pB0 + ko_, dB0 + so_); gload16(pB1 + ko_, dB1 + so_); }

#define G2_TILE(J, DOSTAGE, TRAIL) { \
    const int slot_ = (J) & 3; \
    const char* rA_ = ldsA_rd + slot_ * 24576; \
    const char* rB_ = ldsB_rd + slot_ * 24576; \
    short8 av[4], bv[4]; \
    _Pragma("unroll") for (int i_ = 0; i_ < 4; ++i_) av[i_] = *(const short8*)(rA_ + i_ * 1024); \
    _Pragma("unroll") for (int j_ = 0; j_ < 4; ++j_) bv[j_] = *(const short8*)(rB_ + j_ * 1024); \
    if (DOSTAGE) { STAGE2((J) + 3); } \
    SBAR(); \
    __builtin_amdgcn_s_setprio(1); \
    MFMA16(acc, av, bv); \
    __builtin_amdgcn_s_setprio(0); \
    TRAIL; \
}

__global__ __launch_bounds__(512, 2) void gemm2_kernel(const unsigned short* __restrict__ A,
                                                       const unsigned short* __restrict__ Bt,
                                                       const float* __restrict__ bias,
                                                       float* __restrict__ out_f,
                                                       const float* __restrict__ resid) {
    __shared__ __align__(16) unsigned short lds[4][12288];   // 96 KB
    const int K = D_MODEL;

    int t = threadIdx.x;
    int lane = t & 63;
    int wave = t >> 6;
    int wm = wave >> 2;
    int wn = wave & 3;

    int bid = blockIdx.x;
    int swz = (bid & 7) * 32 + (bid >> 3);
    int m0 = (swz >> 2) * 128;
    int n0 = (swz & 3) * 256;

    int srow = lane >> 2;
    int sk = ((lane & 3) * 8) ^ ((lane & 32) >> 1);
    const unsigned short* pA0 = A  + (size_t)(m0 + wave * 16 + srow) * K + sk;
    const unsigned short* pB0 = Bt + (size_t)(n0 + wave * 16 + srow) * K + sk;
    const unsigned short* pB1 = pB0 + (size_t)128 * K;

    unsigned short* dA  = &lds[0][wave * 512];
    unsigned short* dB0 = &lds[0][4096 + wave * 512];
    unsigned short* dB1 = &lds[0][8192 + wave * 512];

    int off_base = (lane & 15) * 64 + (((lane >> 4) * 16) ^ ((lane & 8) * 4));
    const char* ldsA_rd = (const char*)(&lds[0][0]) + wm * 4096 + off_base;
    const char* ldsB_rd = (const char*)(&lds[0][0]) + 8192 + wn * 4096 + off_base;

    f32x4 acc[4][4] = {};

    STAGE2(0); STAGE2(1); STAGE2(2);
    GATE(6);

    #pragma unroll 1
    for (int j = 0; j < 29; ++j) { G2_TILE(j, true, GATE(6)); }
    G2_TILE(29, false, GATE(3));
    G2_TILE(30, false, GATE(0));
    G2_TILE(31, false, (void)0);

    int col = lane & 15;
    int quad = lane >> 4;
    float bs[4];
    #pragma unroll
    for (int jf = 0; jf < 4; ++jf) bs[jf] = bias[n0 + wn * 64 + jf * 16 + col];
    #pragma unroll
    for (int i = 0; i < 4; ++i) {
        #pragma unroll
        for (int r = 0; r < 4; ++r) {
            int m = m0 + wm * 64 + i * 16 + quad * 4 + r;
            const float* rrow = resid + (size_t)m * D_MODEL + n0 + wn * 64 + col;
            float* orow = out_f + (size_t)m * D_MODEL + n0 + wn * 64 + col;
            #pragma unroll
            for (int jf = 0; jf < 4; ++jf) {
                float y = acc[i][jf][r] + bs[jf] + rrow[jf * 16];
                y = fminf(10.0f, fmaxf(-10.0f, y));
                orow[jf * 16] = y;
            }
        }
    }
}

// ============================================================================
// Fused SSM scan (R4, unchanged): scan1 + combine + scan2 in one kernel.
// ============================================================================
__global__ __launch_bounds__(512) void scan_fused_kernel(const unsigned short* __restrict__ u,
                                                         const unsigned short* __restrict__ zs,
                                                         const float* __restrict__ A_log,
                                                         const float* __restrict__ Bp,
                                                         const float* __restrict__ Cp,
                                                         const float* __restrict__ log_dt,
                                                         unsigned short* __restrict__ yz) {
    __shared__ float S[N_CHUNK][D_STATE][17];   // 34,816 B; pad 17 vs bank aliasing

    int bid = blockIdx.x;
    int l  = (bid & 7) * 32 + (bid >> 3);   // bijective XCD-chunk swizzle
    int b  = l >> 6;                         // 0..3
    int dg = l & 63;                         // 0..63
    int t  = threadIdx.x;
    int c  = t >> 4;                         // chunk 0..31
    int dl = t & 15;
    int d  = dg * 16 + dl;

    // params
    float dt = fminf(1.0f, fmaxf(1e-4f, __expf(log_dt[d])));
    float ab[D_STATE];
    #pragma unroll
    for (int n = 0; n < D_STATE; n++) {
        float a = __expf(-__expf(A_log[d * D_STATE + n]) * dt);
        ab[n] = fminf(1.0f - 1e-8f, fmaxf(1e-8f, a));
    }

    // ---- pass 1: local chunk scan, cache u in registers ----
    size_t row0 = (size_t)(b * L_SEQ + c * C_LEN);
    const unsigned short* up = u + row0 * D_MODEL + d;

    unsigned int uc[32];          // 64 bf16 packed as 32 x u32
    float P[D_STATE];
    #pragma unroll
    for (int n = 0; n < D_STATE; n++) P[n] = 0.0f;
    #pragma unroll
    for (int tt = 0; tt < 32; tt++) {
        unsigned int lo = up[(size_t)(2 * tt) * D_MODEL];
        unsigned int hi = up[(size_t)(2 * tt + 1) * D_MODEL];
        uc[tt] = lo | (hi << 16);
        float u0 = __uint_as_float(lo << 16);
        float u1 = __uint_as_float(hi << 16);
        #pragma unroll
        for (int n = 0; n < D_STATE; n++) P[n] = fmaf(ab[n], P[n], u0);
        #pragma unroll
        for (int n = 0; n < D_STATE; n++) P[n] = fmaf(ab[n], P[n], u1);
    }

    // publish chunk-final states
    #pragma unroll
    for (int n = 0; n < D_STATE; n++) S[c][n][dl] = P[n];

    // aP = a^64 (uniform across chunks -> constant-coefficient prefix valid)
    float m[D_STATE];
    #pragma unroll
    for (int n = 0; n < D_STATE; n++) {
        float a2 = ab[n];
        #pragma unroll
        for (int q = 0; q < 6; q++) a2 = a2 * a2;
        m[n] = a2;
    }
    __syncthreads();

    // ---- Hillis-Steele inclusive prefix over c: P[c] += m * P[c-k] ----
    #pragma unroll
    for (int k = 1; k < N_CHUNK; k <<= 1) {
        float tmp[D_STATE];
        #pragma unroll
        for (int n = 0; n < D_STATE; n++) tmp[n] = (c >= k) ? S[c - k][n][dl] : 0.0f;
        __syncthreads();
        #pragma unroll
        for (int n = 0; n < D_STATE; n++) {
            P[n] = fmaf(m[n], tmp[n], P[n]);
            S[c][n][dl] = P[n];
        }
        #pragma unroll
        for (int n = 0; n < D_STATE; n++) m[n] = m[n] * m[n];
        __syncthreads();
    }

    // ---- pass 2: rescan with exclusive prefix init, fuse z-gate ----
    float s2[D_STATE];
    #pragma unroll
    for (int n = 0; n < D_STATE; n++) s2[n] = (c == 0) ? 0.0f : S[c - 1][n][dl];

    float cb[D_STATE];
    #pragma unroll
    for (int n = 0; n < D_STATE; n++)
        cb[n] = Cp[d * D_STATE + n] * Bp[d * D_STATE + n] * dt;

    const unsigned short* zp = zs + row0 * D_MODEL + d;
    unsigned short* yp = yz + row0 * D_MODEL + d;

    #pragma unroll
    for (int tt = 0; tt < 32; tt++) {
        unsigned int w = uc[tt];
        float u0 = __uint_as_float(w << 16);
        float u1 = __uint_as_float(w & 0xFFFF0000u);
        float y0 = 0.0f, y1 = 0.0f;
        #pragma unroll
        for (int n = 0; n < D_STATE; n++) s2[n] = fmaf(ab[n], s2[n], u0);
        #pragma unroll
        for (int n = 0; n < D_STATE; n++) y0 = fmaf(cb[n], s2[n], y0);
        #pragma unroll
        for (int n = 0; n < D_STATE; n++) s2[n] = fmaf(ab[n], s2[n], u1);
        #pragma unroll
        for (int n = 0; n < D_STATE; n++) y1 = fmaf(cb[n], s2[n], y1);
        float z0 = bf2f(zp[(size_t)(2 * tt) * D_MODEL]);
        float z1 = bf2f(zp[(size_t)(2 * tt + 1) * D_MODEL]);
        yp[(size_t)(2 * tt) * D_MODEL]     = f2bf(y0 * z0);
        yp[(size_t)(2 * tt + 1) * D_MODEL] = f2bf(y1 * z1);
    }
}

extern "C" void kernel_launch(void* const* d_in, const int* in_sizes, int n_in,
                              void* d_out, int out_size, void* d_ws, size_t ws_size,
                              hipStream_t stream) {
    const float* x       = (const float*)d_in[0];
    const float* A_log   = (const float*)d_in[1];
    const float* B_param = (const float*)d_in[2];
    const float* C_param = (const float*)d_in[3];
    const float* log_dt  = (const float*)d_in[4];
    const float* in_w    = (const float*)d_in[5];
    const float* in_b    = (const float*)d_in[6];
    const float* out_w   = (const float*)d_in[7];
    const float* out_b   = (const float*)d_in[8];
    const float* ln_g    = (const float*)d_in[9];
    const float* ln_b    = (const float*)d_in[10];
    float* out = (float*)d_out;

    char* ws = (char*)d_ws;
    size_t off = 0;
    unsigned short* xn = (unsigned short*)(ws + off); off += (size_t)M_ROWS * D_MODEL * 2;        // 16 MB
    unsigned short* w1 = (unsigned short*)(ws + off); off += (size_t)2 * D_MODEL * D_MODEL * 2;   // 4 MB
    unsigned short* u  = (unsigned short*)(ws + off); off += (size_t)M_ROWS * D_MODEL * 2;        // 16 MB
    unsigned short* zs = (unsigned short*)(ws + off); off += (size_t)M_ROWS * D_MODEL * 2;        // 16 MB
    unsigned short* yz = (unsigned short*)(ws + off); off += (size_t)M_ROWS * D_MODEL * 2;        // 16 MB
    unsigned short* w2 = (unsigned short*)(ws + off); off += (size_t)D_MODEL * D_MODEL * 2;       // 2 MB

    // fused LN + weight conversion
    prep_kernel<<<M_ROWS + 2048 + 1024, 256, 0, stream>>>(x, ln_g, ln_b, xn, in_w, w1, out_w, w2);

    // GEMM1: (8192x1024) @ (2048x1024)^T -> u bf16 / silu(z) bf16
    gemm1_kernel<<<256, 512, 0, stream>>>(xn, w1, in_b, u, zs);

    // fused chunked SSM scan
    scan_fused_kernel<<<256, 512, 0, stream>>>(u, zs, A_log, B_param, C_param, log_dt, yz);

    // GEMM2: (8192x1024) @ (1024x1024)^T + resid, clip
    gemm2_kernel<<<256, 512, 0, stream>>>(yz, w2, out_b, out, x);
}